// Round 4
// baseline (1186.371 us; speedup 1.0000x reference)
//
#include <hip/hip_runtime.h>

// ---------------------------------------------------------------------------
// TTT base module: out = (scan(XC,XB,XA,coeff) ) @ Wo^T
// Scan v4: K=16 MFMAs, W1 state in C-layout accumulators (C-layout == B-frag
// for K=16 => in-register bf16 repack, no LDS round-trip). Padded LDS
// (stride 72 shorts) kills the v3 bank conflicts. Double-buffered staging:
// chunk c+1 staged mid-iteration c, so iteration start reads hit ready LDS.
// Single fused 6-sum butterfly for LN-bwd. Output packed via LDS ->
// 2 coalesced 16B global stores. b1 folded into MFMA acc init.
// ---------------------------------------------------------------------------

typedef __attribute__((ext_vector_type(4))) float float4v;
typedef __attribute__((ext_vector_type(4))) short short4v;
typedef __attribute__((ext_vector_type(2))) unsigned int uint2v;
typedef __attribute__((ext_vector_type(4))) unsigned int uint4v;
typedef __attribute__((ext_vector_type(8))) __bf16 bf16x8;

__device__ __forceinline__ unsigned short f2bf(float f) {
  unsigned int u = __builtin_bit_cast(unsigned int, f);
  u += 0x7FFFu + ((u >> 16) & 1u);
  return (unsigned short)(u >> 16);
}
__device__ __forceinline__ float bf2f(unsigned short s) {
  unsigned int u = ((unsigned int)s) << 16;
  return __builtin_bit_cast(float, u);
}
__device__ __forceinline__ unsigned int pkbf(float a, float b) {
  const unsigned int ua = __builtin_bit_cast(unsigned int, a) + 0x8000u;
  const unsigned int ub = __builtin_bit_cast(unsigned int, b) + 0x8000u;
  return __builtin_amdgcn_perm(ub, ua, 0x07060302u);
}
__device__ __forceinline__ short4v pkbf4(float4v v) {
  uint2v u;
  u[0] = pkbf(v[0], v[1]);
  u[1] = pkbf(v[2], v[3]);
  return __builtin_bit_cast(short4v, u);
}
__device__ __forceinline__ void lds_load16(const void* g, void* l) {
  __builtin_amdgcn_global_load_lds((const __attribute__((address_space(1))) void*)g,
                                   (__attribute__((address_space(3))) void*)l, 16, 0, 0);
}

__device__ __forceinline__ void store_out(float* p, float v) { *p = v; }
__device__ __forceinline__ void store_out(unsigned short* p, float v) { *p = f2bf(v); }

// ---------------------------------------------------------------------------
// C[m,n] = sum_k A[m,k] * B[n,k]   (bf16, B^T GEMM, 128x128 tile, BK=32)
// ---------------------------------------------------------------------------
template <typename OUT>
__global__ __launch_bounds__(256) void gemm_bt(
    const unsigned short* __restrict__ A, const unsigned short* __restrict__ B,
    OUT* __restrict__ C, int M, int N, int K) {
  __shared__ unsigned short sA[128 * 32];
  __shared__ unsigned short sB[128 * 32];
  const int tid = threadIdx.x;
  const int wave = tid >> 6;
  const int lane = tid & 63;
  const int quad = lane >> 4;
  const int l15 = lane & 15;
  const int wm = (wave >> 1) * 64;
  const int wn = (wave & 1) * 64;
  const int bm = blockIdx.y * 128;
  const int bn = blockIdx.x * 128;

  float4v acc[4][4];
#pragma unroll
  for (int i = 0; i < 4; ++i)
#pragma unroll
    for (int j = 0; j < 4; ++j) acc[i][j] = (float4v){0.f, 0.f, 0.f, 0.f};

  const int srow = tid >> 2;
  const int scol = (tid & 3) * 8;
  const unsigned short* aptr = A + (size_t)(bm + srow) * K + scol;
  const unsigned short* bptr = B + (size_t)(bn + srow) * K + scol;
  unsigned short* sAw0 = &sA[wave * 512];
  unsigned short* sAw1 = &sA[2048 + wave * 512];
  unsigned short* sBw0 = &sB[wave * 512];
  unsigned short* sBw1 = &sB[2048 + wave * 512];
  const size_t astep = (size_t)64 * K;

  for (int kt = 0; kt < K; kt += 32) {
    __syncthreads();
    lds_load16(aptr + kt, sAw0);
    lds_load16(aptr + kt + astep, sAw1);
    lds_load16(bptr + kt, sBw0);
    lds_load16(bptr + kt + astep, sBw1);
    __syncthreads();
    bf16x8 af[4], bf[4];
#pragma unroll
    for (int i = 0; i < 4; ++i)
      af[i] = *(const bf16x8*)&sA[(wm + i * 16 + l15) * 32 + quad * 8];
#pragma unroll
    for (int j = 0; j < 4; ++j)
      bf[j] = *(const bf16x8*)&sB[(wn + j * 16 + l15) * 32 + quad * 8];
#pragma unroll
    for (int i = 0; i < 4; ++i)
#pragma unroll
      for (int j = 0; j < 4; ++j)
        acc[i][j] = __builtin_amdgcn_mfma_f32_16x16x32_bf16(af[i], bf[j], acc[i][j], 0, 0, 0);
  }

#pragma unroll
  for (int i = 0; i < 4; ++i) {
    const int row0 = bm + wm + i * 16 + quad * 4;
#pragma unroll
    for (int j = 0; j < 4; ++j) {
      const int col = bn + wn + j * 16 + l15;
#pragma unroll
      for (int r = 0; r < 4; ++r)
        store_out(&C[(size_t)(row0 + r) * N + col], acc[i][j][r]);
    }
  }
}

// ---------------------------------------------------------------------------
__global__ __launch_bounds__(256) void f32_to_bf16_k(const float* __restrict__ s,
                                                     unsigned short* __restrict__ d, int n) {
  const int i = (blockIdx.x * 256 + threadIdx.x) * 8;
  if (i >= n) return;
  const float4v a = *(const float4v*)(s + i);
  const float4v b = *(const float4v*)(s + i + 4);
  uint4v o;
  o[0] = (unsigned int)f2bf(a[0]) | ((unsigned int)f2bf(a[1]) << 16);
  o[1] = (unsigned int)f2bf(a[2]) | ((unsigned int)f2bf(a[3]) << 16);
  o[2] = (unsigned int)f2bf(b[0]) | ((unsigned int)f2bf(b[1]) << 16);
  o[3] = (unsigned int)f2bf(b[2]) | ((unsigned int)f2bf(b[3]) << 16);
  *(uint4v*)(d + i) = o;
}

// ---------------------------------------------------------------------------
__global__ __launch_bounds__(256) void coeff_k(const unsigned short* __restrict__ ilr,
                                               const float* __restrict__ lb,
                                               float* __restrict__ coeff) {
  const int gid = blockIdx.x * 256 + threadIdx.x;
  const int row = gid >> 5;
  const int h = gid & 31;
  const float v = bf2f(ilr[row * 128 + h]) + lb[h];
  const float sig = 1.0f / (1.0f + __expf(-v));
  const int b = row >> 11;
  const int pos = row & 2047;
  const int cc = pos >> 4;
  const int k = pos & 15;
  coeff[((((size_t)b * 32 + h) * 128 + cc) << 4) + k] = sig / (64.0f * (float)(k + 1));
}

// ---------------------------------------------------------------------------
// TTT scan v4
// ---------------------------------------------------------------------------
#define SXP 72  // bf16 LDS row stride (shorts): 144B = 4-bank offset per row

__global__ __launch_bounds__(64, 1) void ttt_scan(
    const unsigned short* __restrict__ XC, const unsigned short* __restrict__ XB,
    const unsigned short* __restrict__ XA, const float* __restrict__ coeff,
    const float* __restrict__ lnw, const float* __restrict__ lnb,
    const float* __restrict__ W1i, const float* __restrict__ b1i,
    unsigned short* __restrict__ XCW) {
  const int b = blockIdx.x >> 5;
  const int h = blockIdx.x & 31;
  const int lane = threadIdx.x;
  const int quad = lane >> 4;
  const int l15 = lane & 15;

  __shared__ unsigned short sXC[2][16 * SXP];  // raw bf16 [t][f], padded
  __shared__ unsigned short sXB[2][16 * SXP];
  __shared__ float sTs[2][16 * 68];            // (xa-xb) f32 [t][f]
  __shared__ float sAttn[16 * 20];
  __shared__ unsigned short sOut[16 * 64];     // output pack buffer

  float gam[4], bet[4], gam2[4], gb[4], b1v[4];
#pragma unroll
  for (int nt = 0; nt < 4; ++nt) {
    gam[nt] = lnw[h * 64 + nt * 16 + l15];
    bet[nt] = lnb[h * 64 + nt * 16 + l15];
    gam2[nt] = gam[nt] * gam[nt];
    gb[nt] = gam[nt] * bet[nt];
    b1v[nt] = b1i[h * 64 + nt * 16 + l15];
  }
  float G2 = gam2[0] + gam2[1] + gam2[2] + gam2[3];
#pragma unroll
  for (int m = 1; m <= 8; m <<= 1) G2 += __shfl_xor(G2, m);

  // W1 state, C-layout per tile (mt,nt): elem (f=16mt+quad*4+r, g=16nt+l15)
  float4v W1r[16];
  short4v w1b[16];
#pragma unroll
  for (int mt = 0; mt < 4; ++mt)
#pragma unroll
    for (int nt = 0; nt < 4; ++nt) {
      float4v v;
#pragma unroll
      for (int r = 0; r < 4; ++r)
        v[r] = W1i[(size_t)h * 4096 + (size_t)(mt * 16 + quad * 4 + r) * 64 + nt * 16 + l15];
      W1r[mt * 4 + nt] = v;
      w1b[mt * 4 + nt] = pkbf4(v);
    }

  const int srow = lane >> 2;        // 0..15
  const int scol = (lane & 3) * 16;  // 0,16,32,48
  const size_t hdoff = (size_t)h * 64;
  const size_t browoff = (size_t)b * 2048;
  const size_t cobase = (((size_t)b * 32 + h) * 128) * 16;
  const float inv64 = 1.0f / 64.0f;
  const float4v zero4 = {0.f, 0.f, 0.f, 0.f};

  // output readback/store geometry
  const int orow = lane >> 3;          // 0..7
  const int ocol = (lane & 7) * 8;     // 0..56

  uint4v pxc0, pxc1, pxb0, pxb1, pxa0, pxa1;
  float co_cur, co_stage;

  // ---- load chunk 0, stage into buf0 ----
  {
    const size_t goff = (browoff + (size_t)srow) * 2048 + hdoff + scol;
    pxc0 = *(const uint4v*)(XC + goff);
    pxc1 = *(const uint4v*)(XC + goff + 8);
    pxb0 = *(const uint4v*)(XB + goff);
    pxb1 = *(const uint4v*)(XB + goff + 8);
    pxa0 = *(const uint4v*)(XA + goff);
    pxa1 = *(const uint4v*)(XA + goff + 8);
    co_cur = coeff[cobase + l15];
  }
  {
    *(uint4v*)&sXC[0][srow * SXP + scol] = pxc0;
    *(uint4v*)&sXC[0][srow * SXP + scol + 8] = pxc1;
    *(uint4v*)&sXB[0][srow * SXP + scol] = pxb0;
    *(uint4v*)&sXB[0][srow * SXP + scol + 8] = pxb1;
#pragma unroll
    for (int t2 = 0; t2 < 4; ++t2) {
      float4v tv;
      tv[0] = __builtin_bit_cast(float, pxa0[t2] << 16) - __builtin_bit_cast(float, pxb0[t2] << 16);
      tv[1] = __builtin_bit_cast(float, pxa0[t2] & 0xFFFF0000u) -
              __builtin_bit_cast(float, pxb0[t2] & 0xFFFF0000u);
      tv[2] = __builtin_bit_cast(float, pxa0[(t2 + 1) & 3] << 16) -
              __builtin_bit_cast(float, pxb0[(t2 + 1) & 3] << 16);
      // NOTE: rewritten below properly; placeholder never used
      (void)tv;
      break;
    }
    // proper tgt staging (pairs per dword)
    float tvv[16];
#pragma unroll
    for (int t2 = 0; t2 < 4; ++t2) {
      tvv[t2 * 2] = __builtin_bit_cast(float, pxa0[t2] << 16) -
                    __builtin_bit_cast(float, pxb0[t2] << 16);
      tvv[t2 * 2 + 1] = __builtin_bit_cast(float, pxa0[t2] & 0xFFFF0000u) -
                        __builtin_bit_cast(float, pxb0[t2] & 0xFFFF0000u);
      tvv[8 + t2 * 2] = __builtin_bit_cast(float, pxa1[t2] << 16) -
                        __builtin_bit_cast(float, pxb1[t2] << 16);
      tvv[8 + t2 * 2 + 1] = __builtin_bit_cast(float, pxa1[t2] & 0xFFFF0000u) -
                            __builtin_bit_cast(float, pxb1[t2] & 0xFFFF0000u);
    }
#pragma unroll
    for (int k4 = 0; k4 < 4; ++k4)
      *(float4v*)&sTs[0][srow * 68 + scol + k4 * 4] =
          (float4v){tvv[k4 * 4], tvv[k4 * 4 + 1], tvv[k4 * 4 + 2], tvv[k4 * 4 + 3]};
  }
  // ---- prefetch chunk 1 ----
  {
    const size_t goff = (browoff + (size_t)(16 + srow)) * 2048 + hdoff + scol;
    pxc0 = *(const uint4v*)(XC + goff);
    pxc1 = *(const uint4v*)(XC + goff + 8);
    pxb0 = *(const uint4v*)(XB + goff);
    pxb1 = *(const uint4v*)(XB + goff + 8);
    pxa0 = *(const uint4v*)(XA + goff);
    pxa1 = *(const uint4v*)(XA + goff + 8);
    co_stage = coeff[cobase + 16 + l15];
  }

  for (int c = 0; c < 128; ++c) {
    const int cur = c & 1;
    const int nxt = cur ^ 1;

    // ---- fragment + operand reads from current (pre-staged) buffer ----
    short4v xbA[4], xcA[4];
#pragma unroll
    for (int mt = 0; mt < 4; ++mt) {
      xbA[mt] = *(const short4v*)&sXB[cur][l15 * SXP + mt * 16 + quad * 4];
      xcA[mt] = *(const short4v*)&sXC[cur][l15 * SXP + mt * 16 + quad * 4];
    }
    float gbt[4][4];  // first holds tgt, then gam*(bet - tgt)
#pragma unroll
    for (int nt = 0; nt < 4; ++nt)
#pragma unroll
      for (int r = 0; r < 4; ++r)
        gbt[nt][r] = sTs[cur][(quad * 4 + r) * 68 + nt * 16 + l15];
    float cof[4];
#pragma unroll
    for (int r = 0; r < 4; ++r) cof[r] = __shfl(co_cur, quad * 4 + r);
    short4v caf[4];
#pragma unroll
    for (int mt = 0; mt < 4; ++mt) {
      float4v cv;
#pragma unroll
      for (int jj = 0; jj < 4; ++jj) {
        const unsigned int raw = sXB[cur][(quad * 4 + jj) * SXP + mt * 16 + l15];
        cv[jj] = -cof[jj] * __builtin_bit_cast(float, raw << 16);
      }
      caf[mt] = pkbf4(cv);
    }

    // ---- Z1 = xb@W1 + b1 (acc-init b1) ----
    float4v z[4];
#pragma unroll
    for (int nt = 0; nt < 4; ++nt) {
      float4v t = {b1v[nt], b1v[nt], b1v[nt], b1v[nt]};
      t = __builtin_amdgcn_mfma_f32_16x16x16bf16_1k(xbA[0], w1b[nt], t, 0, 0, 0);
      t = __builtin_amdgcn_mfma_f32_16x16x16bf16_1k(xbA[1], w1b[4 + nt], t, 0, 0, 0);
      t = __builtin_amdgcn_mfma_f32_16x16x16bf16_1k(xbA[2], w1b[8 + nt], t, 0, 0, 0);
      t = __builtin_amdgcn_mfma_f32_16x16x16bf16_1k(xbA[3], w1b[12 + nt], t, 0, 0, 0);
      z[nt] = t;
    }
    // ---- zb = xc@W1 + b1 (off-chain) ----
    float4v zb[4];
#pragma unroll
    for (int nt = 0; nt < 4; ++nt) {
      float4v t = {b1v[nt], b1v[nt], b1v[nt], b1v[nt]};
      t = __builtin_amdgcn_mfma_f32_16x16x16bf16_1k(xcA[0], w1b[nt], t, 0, 0, 0);
      t = __builtin_amdgcn_mfma_f32_16x16x16bf16_1k(xcA[1], w1b[4 + nt], t, 0, 0, 0);
      t = __builtin_amdgcn_mfma_f32_16x16x16bf16_1k(xcA[2], w1b[8 + nt], t, 0, 0, 0);
      t = __builtin_amdgcn_mfma_f32_16x16x16bf16_1k(xcA[3], w1b[12 + nt], t, 0, 0, 0);
      zb[nt] = t;
    }
    // ---- Attn = xc@xb^T (off-chain) ----
    float4v at = __builtin_amdgcn_mfma_f32_16x16x16bf16_1k(xcA[0], xbA[0], zero4, 0, 0, 0);
    at = __builtin_amdgcn_mfma_f32_16x16x16bf16_1k(xcA[1], xbA[1], at, 0, 0, 0);
    at = __builtin_amdgcn_mfma_f32_16x16x16bf16_1k(xcA[2], xbA[2], at, 0, 0, 0);
    at = __builtin_amdgcn_mfma_f32_16x16x16bf16_1k(xcA[3], xbA[3], at, 0, 0, 0);
#pragma unroll
    for (int r = 0; r < 4; ++r) sAttn[(quad * 4 + r) * 20 + l15] = at[r];

    // ---- stage chunk c+1 into nxt buffer; prefetch chunk c+2 ----
    {
      *(uint4v*)&sXC[nxt][srow * SXP + scol] = pxc0;
      *(uint4v*)&sXC[nxt][srow * SXP + scol + 8] = pxc1;
      *(uint4v*)&sXB[nxt][srow * SXP + scol] = pxb0;
      *(uint4v*)&sXB[nxt][srow * SXP + scol + 8] = pxb1;
      float tvv[16];
#pragma unroll
      for (int t2 = 0; t2 < 4; ++t2) {
        tvv[t2 * 2] = __builtin_bit_cast(float, pxa0[t2] << 16) -
                      __builtin_bit_cast(float, pxb0[t2] << 16);
        tvv[t2 * 2 + 1] = __builtin_bit_cast(float, pxa0[t2] & 0xFFFF0000u) -
                          __builtin_bit_cast(float, pxb0[t2] & 0xFFFF0000u);
        tvv[8 + t2 * 2] = __builtin_bit_cast(float, pxa1[t2] << 16) -
                          __builtin_bit_cast(float, pxb1[t2] << 16);
        tvv[8 + t2 * 2 + 1] = __builtin_bit_cast(float, pxa1[t2] & 0xFFFF0000u) -
                              __builtin_bit_cast(float, pxb1[t2] & 0xFFFF0000u);
      }
#pragma unroll
      for (int k4 = 0; k4 < 4; ++k4)
        *(float4v*)&sTs[nxt][srow * 68 + scol + k4 * 4] =
            (float4v){tvv[k4 * 4], tvv[k4 * 4 + 1], tvv[k4 * 4 + 2], tvv[k4 * 4 + 3]};
    }
    const float co_next = co_stage;
    {
      const int cn = (c < 126) ? c + 2 : 127;
      const size_t goff = (browoff + (size_t)(cn * 16 + srow)) * 2048 + hdoff + scol;
      pxc0 = *(const uint4v*)(XC + goff);
      pxc1 = *(const uint4v*)(XC + goff + 8);
      pxb0 = *(const uint4v*)(XB + goff);
      pxb1 = *(const uint4v*)(XB + goff + 8);
      pxa0 = *(const uint4v*)(XA + goff);
      pxa1 = *(const uint4v*)(XA + goff + 8);
      co_stage = coeff[cobase + (size_t)cn * 16 + l15];
    }

    // ---- fused LN-bwd sums: 6 concurrent reductions ----
    float s1[4], s2[4], a1[4], a2[4], c1[4], c2[4];
#pragma unroll
    for (int r = 0; r < 4; ++r) {
      s1[r] = 0.f; s2[r] = 0.f; a1[r] = 0.f; a2[r] = 0.f; c1[r] = 0.f; c2[r] = 0.f;
    }
#pragma unroll
    for (int nt = 0; nt < 4; ++nt)
#pragma unroll
      for (int r = 0; r < 4; ++r) {
        const float zv = z[nt][r];
        const float zz = zv * zv;
        const float gt = gb[nt] - gam[nt] * gbt[nt][r];  // gam*(bet - tgt)
        gbt[nt][r] = gt;
        s1[r] += zv;
        s2[r] += zz;
        a1[r] += gam2[nt] * zv;
        a2[r] += gam2[nt] * zz;
        c1[r] += gt;
        c2[r] += gt * zv;
      }
#pragma unroll
    for (int m = 1; m <= 8; m <<= 1)
#pragma unroll
      for (int r = 0; r < 4; ++r) {
        s1[r] += __shfl_xor(s1[r], m);
        s2[r] += __shfl_xor(s2[r], m);
        a1[r] += __shfl_xor(a1[r], m);
        a2[r] += __shfl_xor(a2[r], m);
        c1[r] += __shfl_xor(c1[r], m);
        c2[r] += __shfl_xor(c2[r], m);
      }
    float mu[4], rstd[4], sg[4], sgx[4];
#pragma unroll
    for (int r = 0; r < 4; ++r) {
      mu[r] = s1[r] * inv64;
      const float var = s2[r] * inv64 - mu[r] * mu[r];
      rstd[r] = rsqrtf(var + 1e-6f);
      sg[r] = rstd[r] * (a1[r] - mu[r] * G2) + c1[r];
      sgx[r] = rstd[r] * rstd[r] * (a2[r] - 2.0f * mu[r] * a1[r] + mu[r] * mu[r] * G2) +
               rstd[r] * (c2[r] - mu[r] * c1[r]);
    }

    // ---- grad ----
    float grad[4][4];
    short4v gradb[4];
#pragma unroll
    for (int nt = 0; nt < 4; ++nt) {
      float4v gv;
#pragma unroll
      for (int r = 0; r < 4; ++r) {
        const float xh = (z[nt][r] - mu[r]) * rstd[r];
        const float ggv = gam2[nt] * xh + gbt[nt][r];
        gv[r] = (64.0f * ggv - sg[r] - xh * sgx[r]) * (rstd[r] * inv64);
        grad[nt][r] = gv[r];
      }
      gradb[nt] = pkbf4(gv);
    }

    // ---- W1 update FIRST (unblocks next iteration's chain) ----
#pragma unroll
    for (int mt = 0; mt < 4; ++mt)
#pragma unroll
      for (int nt = 0; nt < 4; ++nt) {
        W1r[mt * 4 + nt] =
            __builtin_amdgcn_mfma_f32_16x16x16bf16_1k(caf[mt], gradb[nt], W1r[mt * 4 + nt], 0, 0, 0);
        w1b[mt * 4 + nt] = pkbf4(W1r[mt * 4 + nt]);
      }
    // ---- b1 update ----
#pragma unroll
    for (int nt = 0; nt < 4; ++nt) {
      float pb = cof[0] * grad[nt][0] + cof[1] * grad[nt][1] + cof[2] * grad[nt][2] +
                 cof[3] * grad[nt][3];
      pb += __shfl_xor(pb, 16);
      pb += __shfl_xor(pb, 32);
      b1v[nt] -= pb;
    }

    // ---- m1f = -((Attn+1) o E) ----
    const float4v av = *(const float4v*)&sAttn[l15 * 20 + quad * 4];
    short4v m1f;
    {
      float4v mv;
#pragma unroll
      for (int jj = 0; jj < 4; ++jj) {
        const int k = quad * 4 + jj;
        const float e = (k <= l15) ? cof[jj] : 0.0f;
        mv[jj] = -(av[jj] + 1.0f) * e;
      }
      m1f = pkbf4(mv);
    }

    // ---- Z1_bar = zb + m1f@gradb ----
    float4v zr[4];
#pragma unroll
    for (int nt = 0; nt < 4; ++nt)
      zr[nt] = __builtin_amdgcn_mfma_f32_16x16x16bf16_1k(m1f, gradb[nt], zb[nt], 0, 0, 0);

    // ---- LN2 + out ----
    float t1[4], t2s[4];
#pragma unroll
    for (int r = 0; r < 4; ++r) {
      t1[r] = zr[0][r] + zr[1][r] + zr[2][r] + zr[3][r];
      t2s[r] = zr[0][r] * zr[0][r] + zr[1][r] * zr[1][r] + zr[2][r] * zr[2][r] +
               zr[3][r] * zr[3][r];
    }
#pragma unroll
    for (int m = 1; m <= 8; m <<= 1)
#pragma unroll
      for (int r = 0; r < 4; ++r) {
        t1[r] += __shfl_xor(t1[r], m);
        t2s[r] += __shfl_xor(t2s[r], m);
      }
#pragma unroll
    for (int r = 0; r < 4; ++r) {
      const float mu2 = t1[r] * inv64;
      const float var = t2s[r] * inv64 - mu2 * mu2;
      const float rs = rsqrtf(var + 1e-6f);
#pragma unroll
      for (int nt = 0; nt < 4; ++nt) {
        const float xhat = (zr[nt][r] - mu2) * rs;
        const float y = gam[nt] * xhat + bet[nt];
        const float xcv = bf2f(sXC[cur][(quad * 4 + r) * SXP + nt * 16 + l15]);
        sOut[(quad * 4 + r) * 64 + nt * 16 + l15] = f2bf(xcv + y);
      }
    }
    // coalesced store: 2 x 16B per lane
    {
      const uint4v o0 = *(const uint4v*)&sOut[orow * 64 + ocol];
      const uint4v o1 = *(const uint4v*)&sOut[(orow + 8) * 64 + ocol];
      *(uint4v*)(XCW + (browoff + (size_t)(c * 16 + orow)) * 2048 + hdoff + ocol) = o0;
      *(uint4v*)(XCW + (browoff + (size_t)(c * 16 + orow + 8)) * 2048 + hdoff + ocol) = o1;
    }
    co_cur = co_next;
  }
}

// ---------------------------------------------------------------------------
extern "C" void kernel_launch(void* const* d_in, const int* in_sizes, int n_in,
                              void* d_out, int out_size, void* d_ws, size_t ws_size,
                              hipStream_t stream) {
  const float* hs = (const float*)d_in[0];
  const float* Wq = (const float*)d_in[1];
  const float* Wk = (const float*)d_in[2];
  const float* Wv = (const float*)d_in[3];
  const float* Wo = (const float*)d_in[4];
  const float* lw = (const float*)d_in[5];
  const float* lb = (const float*)d_in[6];
  const float* lnw = (const float*)d_in[7];
  const float* lnb = (const float*)d_in[8];
  const float* W1i = (const float*)d_in[9];
  const float* b1i = (const float*)d_in[10];
  float* out = (float*)d_out;
  char* ws = (char*)d_ws;

  unsigned short* hsb = (unsigned short*)(ws);               // 33554432 (hs bf16; reused as XCW)
  unsigned short* wqb = (unsigned short*)(ws + 33554432);    // 8388608
  unsigned short* wkb = (unsigned short*)(ws + 41943040);    // 8388608
  unsigned short* wvb = (unsigned short*)(ws + 50331648);    // 8388608
  unsigned short* wob = (unsigned short*)(ws + 58720256);    // 8388608
  unsigned short* lwb = (unsigned short*)(ws + 67108864);    // 524288
  unsigned short* XCb = (unsigned short*)(ws + 67633152);    // 33554432
  unsigned short* XBb = (unsigned short*)(ws + 101187584);   // 33554432
  unsigned short* XAb = (unsigned short*)(ws + 134742016);   // 33554432
  unsigned short* ilrb = (unsigned short*)(ws + 168296448);  // 2097152
  float* coeff = (float*)(ws + 170393600);                   // 1048576

  f32_to_bf16_k<<<8192, 256, 0, stream>>>(hs, hsb, 16777216);
  f32_to_bf16_k<<<2048, 256, 0, stream>>>(Wq, wqb, 4194304);
  f32_to_bf16_k<<<2048, 256, 0, stream>>>(Wk, wkb, 4194304);
  f32_to_bf16_k<<<2048, 256, 0, stream>>>(Wv, wvb, 4194304);
  f32_to_bf16_k<<<2048, 256, 0, stream>>>(Wo, wob, 4194304);
  hipMemsetAsync(lwb, 0, 524288, stream);
  f32_to_bf16_k<<<32, 256, 0, stream>>>(lw, lwb, 65536);

  dim3 blk(256);
  dim3 gbig(16, 64);
  gemm_bt<unsigned short><<<gbig, blk, 0, stream>>>(hsb, wqb, XCb, 8192, 2048, 2048);
  gemm_bt<unsigned short><<<gbig, blk, 0, stream>>>(hsb, wkb, XBb, 8192, 2048, 2048);
  gemm_bt<unsigned short><<<gbig, blk, 0, stream>>>(hsb, wvb, XAb, 8192, 2048, 2048);
  gemm_bt<unsigned short><<<dim3(1, 64), blk, 0, stream>>>(hsb, lwb, ilrb, 8192, 128, 2048);
  coeff_k<<<1024, 256, 0, stream>>>(ilrb, lb, coeff);
  ttt_scan<<<128, 64, 0, stream>>>(XCb, XBb, XAb, coeff, lnw, lnb, W1i, b1i, hsb);
  gemm_bt<float><<<gbig, blk, 0, stream>>>(hsb, wob, out, 8192, 2048, 2048);
}